// Round 11
// baseline (576.209 us; speedup 1.0000x reference)
//
#include <hip/hip_runtime.h>

#define D 256
#define SLOPE 0.01f

// bucket scatter params
#define BSH 9
#define BSZ 512
#define NBMAX 160
#define EPB 8192

typedef __attribute__((ext_vector_type(8))) short bf16x8;
typedef __attribute__((ext_vector_type(4))) float f32x4;

__device__ __forceinline__ float bfbits2f(unsigned int hi) {
  return __builtin_bit_cast(float, hi);
}
__device__ __forceinline__ unsigned short f2bf(float f) {
  unsigned u = __builtin_bit_cast(unsigned, f);
  u += 0x7fffu + ((u >> 16) & 1u);
  return (unsigned short)(u >> 16);
}
__device__ __forceinline__ float lrelu(float x) {
  return (x >= 0.f) ? x : SLOPE * x;
}

__device__ __forceinline__ void gld_lds16(const void* g, void* l) {
  __builtin_amdgcn_global_load_lds(
      (const __attribute__((address_space(1))) unsigned int*)g,
      (__attribute__((address_space(3))) unsigned int*)l, 16, 0, 0);
}

// batched weight cast: 5 weights of D*D floats each
__global__ void cast5_kernel(const float* w0, const float* w1, const float* w2,
                             const float* w3, const float* w4,
                             unsigned short* o0, unsigned short* o1,
                             unsigned short* o2, unsigned short* o3,
                             unsigned short* o4) {
  int a = blockIdx.y;
  const float* in = a == 0 ? w0 : a == 1 ? w1 : a == 2 ? w2 : a == 3 ? w3 : w4;
  unsigned short* out = a == 0 ? o0 : a == 1 ? o1 : a == 2 ? o2 : a == 3 ? o3 : o4;
  int i = blockIdx.x * blockDim.x + threadIdx.x;  // over D*D/4
  float4 v = ((const float4*)in)[i];
  ushort4 o;
  o.x = f2bf(v.x); o.y = f2bf(v.y); o.z = f2bf(v.z); o.w = f2bf(v.w);
  ((ushort4*)out)[i] = o;
}

// ---------------- GEMM building blocks ----------------
// Round-11: per-wave register footprint halved (wf[2][8]=64 regs,
// acc[4][2]=32; each wave does TWO 32-col passes) so 3 waves/EU fit ->
// ~3 blocks/CU resident -> cross-block latency overlap. Rounds 7-10 showed
// per-block serial latency (not traffic) is the GEMM floor at 1.3 blocks/CU.

// bf16 source staging via global_load_lds (used by gemm1).
__device__ __forceinline__ void stage_A(unsigned short* Xs,
                                        const unsigned short* __restrict__ A,
                                        int M, int mblk) {
  const int t = threadIdx.x;
  const int w = t >> 6, lane = t & 63;
#pragma unroll
  for (int i = 0; i < 8; i++) {
    const int m = (i * 4 + w) * 2 + (lane >> 5);
    int row = mblk + m;
    if (row > M - 1) row = M - 1;
    const int jsrc = (lane & 31) ^ (m & 7);
    gld_lds16(A + (size_t)row * D + jsrc * 8, &Xs[(i * 4 + w) * 512]);
  }
}

// fp32 source staging (fused cast): load 32B fp32, convert, 16B swizzled
// ds_write. Same LDS layout: chunk (m,j) -> LDS chunk m*32 + (j^(m&7)).
__device__ __forceinline__ void stage_A_f32(unsigned short* Xs,
                                            const float* __restrict__ A,
                                            int M, int mblk) {
  const int t = threadIdx.x;
#pragma unroll
  for (int c = 0; c < 8; c++) {
    const int chunk = c * 256 + t;
    const int m = chunk >> 5, jg = chunk & 31;
    int row = mblk + m;
    if (row > M - 1) row = M - 1;
    const float* gp = A + (size_t)row * D + jg * 8;
    float4 v0 = *(const float4*)gp;
    float4 v1 = *(const float4*)(gp + 4);
    uint4 pk;
    pk.x = (unsigned)f2bf(v0.x) | ((unsigned)f2bf(v0.y) << 16);
    pk.y = (unsigned)f2bf(v0.z) | ((unsigned)f2bf(v0.w) << 16);
    pk.z = (unsigned)f2bf(v1.x) | ((unsigned)f2bf(v1.y) << 16);
    pk.w = (unsigned)f2bf(v1.z) | ((unsigned)f2bf(v1.w) << 16);
    *(uint4*)&Xs[(m * 32 + (jg ^ (m & 7))) * 8] = pk;
  }
}

// One 64-row x 256-col product off a staged A tile, in TWO 32-col passes
// per wave (cols c*128 + 32w .. +32). SYNC=true: drain staging + barrier
// after the first pass's W loads are issued.
template <int MODE, bool SYNC>
__device__ __forceinline__ void gemm_compute32(
    const unsigned short* Xs, const unsigned short* __restrict__ B,
    const float* __restrict__ bias, const float* __restrict__ residual,
    unsigned short* __restrict__ outb, float* __restrict__ outf, int M,
    int mblk) {
  const int t = threadIdx.x;
  const int w = t >> 6, lane = t & 63;
  const int fr = lane & 15;
  const int jb = lane >> 4;
  const int r = fr & 7;

#pragma unroll
  for (int c = 0; c < 2; c++) {
    const int colbase = c * 128 + w * 32;
    bf16x8 wf[2][8];
    {
      const unsigned short* wp = B + (size_t)(colbase + fr) * D + jb * 8;
#pragma unroll
      for (int nt = 0; nt < 2; nt++)
#pragma unroll
        for (int k0 = 0; k0 < 8; k0++)
          wf[nt][k0] = *(const bf16x8*)(wp + nt * 16 * D + k0 * 32);
    }

    if (SYNC && c == 0) {
      asm volatile("s_waitcnt vmcnt(0)" ::: "memory");
      __syncthreads();
    }

    f32x4 acc[4][2];
#pragma unroll
    for (int i = 0; i < 4; i++)
#pragma unroll
      for (int j = 0; j < 2; j++) acc[i][j] = (f32x4){0.f, 0.f, 0.f, 0.f};

#pragma unroll
    for (int k0 = 0; k0 < 8; k0++) {
      bf16x8 xf[4];
#pragma unroll
      for (int mt = 0; mt < 4; mt++) {
        const int ml = mt * 16 + fr;
        xf[mt] = *(const bf16x8*)&Xs[ml * 256 + (((k0 * 4 + jb) ^ r) * 8)];
      }
#pragma unroll
      for (int mt = 0; mt < 4; mt++)
#pragma unroll
        for (int nt = 0; nt < 2; nt++)
          acc[mt][nt] = __builtin_amdgcn_mfma_f32_16x16x32_bf16(
              wf[nt][k0], xf[mt], acc[mt][nt], 0, 0, 0);
    }

    const int n0 = colbase + jb * 4;
    float4 bv[2];
#pragma unroll
    for (int nt = 0; nt < 2; nt++) bv[nt] = *(const float4*)&bias[n0 + nt * 16];

#pragma unroll
    for (int mt = 0; mt < 4; mt++) {
      const int m = mblk + mt * 16 + fr;
      if (m < M) {
        if (MODE == 1) {
          float4 rv[2];
#pragma unroll
          for (int nt = 0; nt < 2; nt++)
            rv[nt] = *(const float4*)&residual[(size_t)m * D + n0 + nt * 16];
#pragma unroll
          for (int nt = 0; nt < 2; nt++) {
            float4 o;
            o.x = lrelu(acc[mt][nt][0] + bv[nt].x) + rv[nt].x;
            o.y = lrelu(acc[mt][nt][1] + bv[nt].y) + rv[nt].y;
            o.z = lrelu(acc[mt][nt][2] + bv[nt].z) + rv[nt].z;
            o.w = lrelu(acc[mt][nt][3] + bv[nt].w) + rv[nt].w;
            *(float4*)&outf[(size_t)m * D + n0 + nt * 16] = o;
          }
        } else {
#pragma unroll
          for (int nt = 0; nt < 2; nt++) {
            ushort4 o;
            o.x = f2bf(lrelu(acc[mt][nt][0] + bv[nt].x));
            o.y = f2bf(lrelu(acc[mt][nt][1] + bv[nt].y));
            o.z = f2bf(lrelu(acc[mt][nt][2] + bv[nt].z));
            o.w = f2bf(lrelu(acc[mt][nt][3] + bv[nt].w));
            *(ushort4*)&outb[(size_t)m * D + n0 + nt * 16] = o;
          }
        }
      }
    }
  }
}

// Wh = lrelu(feat@W^T+b) for BOTH etypes of one ntype per block, reading
// fp32 feat directly (fused cast). Flattened grid: blocks [0,nbT) = table,
// [nbT, nbT+nbC) = column.
__global__ __launch_bounds__(256, 3) void gemm0_pair(
    const float* __restrict__ A0, const float* __restrict__ A1,
    const unsigned short* __restrict__ B00, const unsigned short* __restrict__ B01,
    const unsigned short* __restrict__ B10, const unsigned short* __restrict__ B11,
    const float* b00, const float* b01, const float* b10, const float* b11,
    unsigned short* o00, unsigned short* o01, unsigned short* o10,
    unsigned short* o11, int M0, int M1, int nbT) {
  __shared__ __attribute__((aligned(16))) unsigned short Xs[64 * 256];
  const int a = (blockIdx.x >= nbT) ? 1 : 0;
  const float* A = a ? A1 : A0;
  const int M = a ? M1 : M0;
  const int mblk = (a ? (blockIdx.x - nbT) : blockIdx.x) * 64;
  stage_A_f32(Xs, A, M, mblk);  // staging first; W loads fill the latency
  gemm_compute32<0, true>(Xs, a ? B10 : B00, a ? b10 : b00, nullptr,
                          a ? o10 : o00, nullptr, M, mblk);
  gemm_compute32<0, false>(Xs, a ? B11 : B01, a ? b11 : b01, nullptr,
                           a ? o11 : o01, nullptr, M, mblk);
}

// both final GEMMs (out = lrelu(h@Wh^T+bh)+feat) in ONE flattened dispatch.
__global__ __launch_bounds__(256, 3) void gemm1_dual(
    const unsigned short* __restrict__ A0, const unsigned short* __restrict__ A1,
    const unsigned short* __restrict__ Bw, const float* bh,
    const float* __restrict__ r0, const float* __restrict__ r1,
    float* __restrict__ o0, float* __restrict__ o1, int M0, int M1, int nbT) {
  __shared__ __attribute__((aligned(16))) unsigned short Xs[64 * 256];
  const int a = (blockIdx.x >= nbT) ? 1 : 0;
  const unsigned short* A = a ? A1 : A0;
  const int M = a ? M1 : M0;
  const int mblk = (a ? (blockIdx.x - nbT) : blockIdx.x) * 64;
  stage_A(Xs, A, M, mblk);
  gemm_compute32<1, true>(Xs, Bw, bh, a ? r1 : r0, nullptr, a ? o1 : o0, M,
                          mblk);
}

// ---------------- counting-sort CSR build ----------------
// Pass 1: per-block LDS histogram over 512-dst buckets.
__global__ __launch_bounds__(256) void bucketCount_kernel(
    const int* d0, int n0, const int* d1, int n1, const int* d2, int n2,
    const int* d3, int n3, int* __restrict__ bcnt) {
  int a = blockIdx.y;
  const int* dst = a == 0 ? d0 : a == 1 ? d1 : a == 2 ? d2 : d3;
  int n = a == 0 ? n0 : a == 1 ? n1 : a == 2 ? n2 : n3;
  int blk = blockIdx.x;
  if (blk * EPB >= n) return;
  int t = threadIdx.x;
  __shared__ int cnt[NBMAX];
  if (t < NBMAX) cnt[t] = 0;
  __syncthreads();
  int i0 = blk * EPB + t;
#pragma unroll 4
  for (int it = 0; it < EPB / 256; it++) {
    int i = i0 + it * 256;
    if (i < n) atomicAdd(&cnt[dst[i] >> BSH], 1);
  }
  __syncthreads();
  if (t < NBMAX && cnt[t]) atomicAdd(&bcnt[a * NBMAX + t], cnt[t]);
}

// Pass 2: one block scans 4x160 bucket totals -> bbase; writes off[nn]=E.
__global__ __launch_bounds__(256) void bucketScan_kernel(
    const int* __restrict__ bcnt, int* __restrict__ bbase,
    int* o0, int n0, int e0, int* o1, int n1, int e1,
    int* o2, int n2, int e2, int* o3, int n3, int e3) {
  __shared__ int s[256];
  int t = threadIdx.x;
  for (int a = 0; a < 4; a++) {
    int v = (t < NBMAX) ? bcnt[a * NBMAX + t] : 0;
    s[t] = v;
    __syncthreads();
    for (int off = 1; off < 256; off <<= 1) {
      int u = (t >= off) ? s[t - off] : 0;
      __syncthreads();
      s[t] += u;
      __syncthreads();
    }
    if (t < NBMAX)
      bbase[a * (NBMAX + 1) + t] = s[t] - v;
    else if (t == NBMAX)
      bbase[a * (NBMAX + 1) + NBMAX] = s[NBMAX - 1];
    __syncthreads();
  }
  if (t == 0) { o0[n0] = e0; o1[n1] = e1; o2[n2] = e2; o3[n3] = e3; }
}

// Pass 3: scatter edges into bucket-grouped temp (packed src<<9|dstlow).
__global__ __launch_bounds__(256) void bucketA_kernel(
    const int* s0, const int* d0, int n0, unsigned* t0,
    const int* s1, const int* d1, int n1, unsigned* t1,
    const int* s2, const int* d2, int n2, unsigned* t2,
    const int* s3, const int* d3, int n3, unsigned* t3,
    const int* __restrict__ bbase, int* __restrict__ bcur) {
  int a = blockIdx.y;
  const int* src = a == 0 ? s0 : a == 1 ? s1 : a == 2 ? s2 : s3;
  const int* dst = a == 0 ? d0 : a == 1 ? d1 : a == 2 ? d2 : d3;
  int n = a == 0 ? n0 : a == 1 ? n1 : a == 2 ? n2 : n3;
  unsigned* temp = a == 0 ? t0 : a == 1 ? t1 : a == 2 ? t2 : t3;

  int blk = blockIdx.x;
  if (blk * EPB >= n) return;
  int t = threadIdx.x;
  __shared__ int cnt[NBMAX];
  __shared__ int lbase[NBMAX];
  if (t < NBMAX) cnt[t] = 0;
  __syncthreads();

  int i0 = blk * EPB + t;
#pragma unroll 4
  for (int it = 0; it < EPB / 256; it++) {
    int i = i0 + it * 256;
    if (i < n) atomicAdd(&cnt[dst[i] >> BSH], 1);
  }
  __syncthreads();
  if (t < NBMAX) {
    int c = cnt[t];
    int g = c ? atomicAdd(&bcur[a * NBMAX + t], c) : 0;
    lbase[t] = g + bbase[a * (NBMAX + 1) + t];
    cnt[t] = 0;
  }
  __syncthreads();
#pragma unroll 4
  for (int it = 0; it < EPB / 256; it++) {
    int i = i0 + it * 256;
    if (i < n) {
      int d = dst[i];
      int b = d >> BSH;
      int rk = atomicAdd(&cnt[b], 1);
      temp[lbase[b] + rk] = ((unsigned)src[i] << BSH) | (unsigned)(d & (BSZ - 1));
    }
  }
}

// Pass 4: one block per bucket: LDS count+scan of 512 dst slots, write
// off[node] (sequential), scatter src into elist (L2-local window).
__global__ __launch_bounds__(256) void bucketFinal_kernel(
    const unsigned* t0, int* o0, int* e0, int m0,
    const unsigned* t1, int* o1, int* e1, int m1,
    const unsigned* t2, int* o2, int* e2, int m2,
    const unsigned* t3, int* o3, int* e3, int m3,
    const int* __restrict__ bbase) {
  int a = blockIdx.y;
  const unsigned* temp = a == 0 ? t0 : a == 1 ? t1 : a == 2 ? t2 : t3;
  int* offs = a == 0 ? o0 : a == 1 ? o1 : a == 2 ? o2 : o3;
  int* elist = a == 0 ? e0 : a == 1 ? e1 : a == 2 ? e2 : e3;
  int nn = a == 0 ? m0 : a == 1 ? m1 : a == 2 ? m2 : m3;

  int nb = (nn + BSZ - 1) >> BSH;
  int b = blockIdx.x;
  if (b >= nb) return;
  int lo = bbase[a * (NBMAX + 1) + b];
  int hi = bbase[a * (NBMAX + 1) + b + 1];
  int t = threadIdx.x;

  __shared__ int cnt[BSZ];
  __shared__ int psum[BSZ];
  __shared__ int sm[256];
  cnt[t] = 0; cnt[t + 256] = 0;
  __syncthreads();
  for (int i = lo + t; i < hi; i += 256)
    atomicAdd(&cnt[temp[i] & (BSZ - 1)], 1);
  __syncthreads();
  int c0 = cnt[2 * t], c1 = cnt[2 * t + 1];
  int s = c0 + c1;
  sm[t] = s;
  __syncthreads();
  for (int off = 1; off < 256; off <<= 1) {
    int u = (t >= off) ? sm[t - off] : 0;
    __syncthreads();
    sm[t] += u;
    __syncthreads();
  }
  int ex = sm[t] - s;
  psum[2 * t] = ex;
  psum[2 * t + 1] = ex + c0;
  cnt[2 * t] = 0; cnt[2 * t + 1] = 0;   // reuse as cursors
  __syncthreads();

  int node0 = b << BSH;
  if (node0 + 2 * t < nn) offs[node0 + 2 * t] = lo + psum[2 * t];
  if (node0 + 2 * t + 1 < nn) offs[node0 + 2 * t + 1] = lo + psum[2 * t + 1];

  for (int i = lo + t; i < hi; i += 256) {
    unsigned v = temp[i];
    int d = v & (BSZ - 1);
    int rk = atomicAdd(&cnt[d], 1);
    elist[lo + psum[d] + rk] = (int)(v >> BSH);
  }
}

// ---------------- aggregation: one wave per dst node, two etypes fused ------
__device__ __forceinline__ void add8(float* acc, uint4 p) {
  acc[0] += bfbits2f(p.x << 16);
  acc[1] += bfbits2f(p.x & 0xffff0000u);
  acc[2] += bfbits2f(p.y << 16);
  acc[3] += bfbits2f(p.y & 0xffff0000u);
  acc[4] += bfbits2f(p.z << 16);
  acc[5] += bfbits2f(p.z & 0xffff0000u);
  acc[6] += bfbits2f(p.w << 16);
  acc[7] += bfbits2f(p.w & 0xffff0000u);
}

__global__ __launch_bounds__(256) void aggregate_kernel(
    const unsigned short* __restrict__ WhA, const int* __restrict__ offsA,
    const int* __restrict__ elistA, const unsigned short* __restrict__ WhB,
    const int* __restrict__ offsB, const int* __restrict__ elistB,
    unsigned short* __restrict__ hout, int n) {
  int wave = (blockIdx.x * 256 + threadIdx.x) >> 6;
  int lane = threadIdx.x & 63;
  if (wave >= n) return;
  int half = lane >> 5;
  int l32 = lane & 31;
  size_t coff = (size_t)l32 * 8;  // channel offset in shorts

  float accA[8] = {0, 0, 0, 0, 0, 0, 0, 0};
  float accB[8] = {0, 0, 0, 0, 0, 0, 0, 0};
  float scA, scB;

  {
    int e0 = offsA[wave], e1 = offsA[wave + 1];
    scA = 0.5f / fmaxf((float)(e1 - e0), 1.0f);
    int e = e0;
    for (; e + 8 <= e1; e += 8) {
      int s0 = elistA[e + half];
      int s1 = elistA[e + 2 + half];
      int s2 = elistA[e + 4 + half];
      int s3 = elistA[e + 6 + half];
      uint4 p0 = *(const uint4*)(WhA + (size_t)s0 * D + coff);
      uint4 p1 = *(const uint4*)(WhA + (size_t)s1 * D + coff);
      uint4 p2 = *(const uint4*)(WhA + (size_t)s2 * D + coff);
      uint4 p3 = *(const uint4*)(WhA + (size_t)s3 * D + coff);
      add8(accA, p0); add8(accA, p1); add8(accA, p2); add8(accA, p3);
    }
    for (; e + 2 <= e1; e += 2) {
      int s0 = elistA[e + half];
      uint4 p0 = *(const uint4*)(WhA + (size_t)s0 * D + coff);
      add8(accA, p0);
    }
    if (e < e1 && half == 0) {
      int s0 = elistA[e];
      uint4 p0 = *(const uint4*)(WhA + (size_t)s0 * D + coff);
      add8(accA, p0);
    }
  }
  {
    int e0 = offsB[wave], e1 = offsB[wave + 1];
    scB = 0.5f / fmaxf((float)(e1 - e0), 1.0f);
    int e = e0;
    for (; e + 8 <= e1; e += 8) {
      int s0 = elistB[e + half];
      int s1 = elistB[e + 2 + half];
      int s2 = elistB[e + 4 + half];
      int s3 = elistB[e + 6 + half];
      uint4 p0 = *(const uint4*)(WhB + (size_t)s0 * D + coff);
      uint4 p1 = *(const uint4*)(WhB + (size_t)s1 * D + coff);
      uint4 p2 = *(const uint4*)(WhB + (size_t)s2 * D + coff);
      uint4 p3 = *(const uint4*)(WhB + (size_t)s3 * D + coff);
      add8(accB, p0); add8(accB, p1); add8(accB, p2); add8(accB, p3);
    }
    for (; e + 2 <= e1; e += 2) {
      int s0 = elistB[e + half];
      uint4 p0 = *(const uint4*)(WhB + (size_t)s0 * D + coff);
      add8(accB, p0);
    }
    if (e < e1 && half == 0) {
      int s0 = elistB[e];
      uint4 p0 = *(const uint4*)(WhB + (size_t)s0 * D + coff);
      add8(accB, p0);
    }
  }

  float h[8];
#pragma unroll
  for (int j = 0; j < 8; j++) {
    h[j] = accA[j] * scA + accB[j] * scB;
    h[j] += __shfl_down(h[j], 32);
  }
  if (half == 0) {
    uint4 o;
    o.x = (unsigned)f2bf(h[0]) | ((unsigned)f2bf(h[1]) << 16);
    o.y = (unsigned)f2bf(h[2]) | ((unsigned)f2bf(h[3]) << 16);
    o.z = (unsigned)f2bf(h[4]) | ((unsigned)f2bf(h[5]) << 16);
    o.w = (unsigned)f2bf(h[6]) | ((unsigned)f2bf(h[7]) << 16);
    *(uint4*)(hout + (size_t)wave * D + coff) = o;
  }
}

// ---------------- launch ----------------
extern "C" void kernel_launch(void* const* d_in, const int* in_sizes, int n_in,
                              void* d_out, int out_size, void* d_ws,
                              size_t ws_size, hipStream_t stream) {
  const float* feat_table = (const float*)d_in[0];
  const float* feat_column = (const float*)d_in[1];
  const float* Wsrc[5] = {(const float*)d_in[2], (const float*)d_in[4],
                          (const float*)d_in[6], (const float*)d_in[8],
                          (const float*)d_in[10]};
  const float* b_t2c = (const float*)d_in[3];
  const float* b_c2t = (const float*)d_in[5];
  const float* b_c2c = (const float*)d_in[7];
  const float* b_t2t = (const float*)d_in[9];
  const float* b_h = (const float*)d_in[11];
  const int* src_t2c = (const int*)d_in[12];
  const int* dst_t2c = (const int*)d_in[13];
  const int* src_c2t = (const int*)d_in[14];
  const int* dst_c2t = (const int*)d_in[15];
  const int* src_c2c = (const int*)d_in[16];
  const int* dst_c2c = (const int*)d_in[17];
  const int* src_t2t = (const int*)d_in[18];
  const int* dst_t2t = (const int*)d_in[19];

  const int NT = in_sizes[0] / D;
  const int NC = in_sizes[1] / D;
  const int E_t2c = in_sizes[12], E_c2t = in_sizes[14];
  const int E_c2c = in_sizes[16], E_t2t = in_sizes[18];

  char* ws = (char*)d_ws;
  size_t cur = 0;
  auto alloc = [&](size_t bytes) -> void* {
    void* p = ws + cur;
    cur += (bytes + 255) & ~(size_t)255;
    return p;
  };
  unsigned short* Wb[5];
  for (int i = 0; i < 5; i++) Wb[i] = (unsigned short*)alloc((size_t)D * D * 2);
  // scratch region: bucket temp (bucketA->bucketFinal), then h_tab/h_col
  // (aggregate->gemm1). Sized for the larger of the two uses.
  size_t scratchA = sizeof(unsigned) * ((size_t)E_c2t + E_t2t + E_t2c + E_c2c);
  size_t scratchB = (size_t)(NT + NC) * D * 2;
  unsigned short* scr = (unsigned short*)alloc(scratchA > scratchB ? scratchA
                                                                   : scratchB);
  unsigned short* Wh_t2c = (unsigned short*)alloc((size_t)NT * D * 2);
  unsigned short* Wh_c2t = (unsigned short*)alloc((size_t)NC * D * 2);
  unsigned short* Wh_c2c = (unsigned short*)alloc((size_t)NC * D * 2);
  unsigned short* Wh_t2t = (unsigned short*)alloc((size_t)NT * D * 2);
  // bucket counters (zeroed): bcnt[4][160] + bcur[4][160]
  int* bcnt = (int*)alloc(sizeof(int) * 2 * 4 * NBMAX);
  int* bcur = bcnt + 4 * NBMAX;
  int* bbase = (int*)alloc(sizeof(int) * 4 * (NBMAX + 1));
  int* off_c2t = (int*)alloc(sizeof(int) * (NT + 1));
  int* off_t2t = (int*)alloc(sizeof(int) * (NT + 1));
  int* off_t2c = (int*)alloc(sizeof(int) * (NC + 1));
  int* off_c2c = (int*)alloc(sizeof(int) * (NC + 1));
  int* el_c2t = (int*)alloc(sizeof(int) * E_c2t);
  int* el_t2t = (int*)alloc(sizeof(int) * E_t2t);
  int* el_t2c = (int*)alloc(sizeof(int) * E_t2c);
  int* el_c2c = (int*)alloc(sizeof(int) * E_c2c);

  // scratch region aliases (lifetimes disjoint; stream serializes)
  unsigned* tp_c2t = (unsigned*)scr;
  unsigned* tp_t2t = tp_c2t + E_c2t;
  unsigned* tp_t2c = tp_t2t + E_t2t;
  unsigned* tp_c2c = tp_t2c + E_t2c;
  unsigned short* h_tab = scr;
  unsigned short* h_col = scr + (size_t)NT * D;

  hipMemsetAsync(bcnt, 0, sizeof(int) * 2 * 4 * NBMAX, stream);

  // weight casts
  {
    dim3 g((D * D / 4 + 255) / 256, 5);
    cast5_kernel<<<g, 256, 0, stream>>>(Wsrc[0], Wsrc[1], Wsrc[2], Wsrc[3],
                                        Wsrc[4], Wb[0], Wb[1], Wb[2], Wb[3],
                                        Wb[4]);
  }

  const int nbT = (NT + 63) / 64, nbC = (NC + 63) / 64;

  // Wh = lrelu(feat @ W^T + b): fp32 feat read directly (fused cast),
  // both etypes per ntype off one staged A tile; flattened grid.
  gemm0_pair<<<nbT + nbC, 256, 0, stream>>>(
      feat_table, feat_column, Wb[0], Wb[3], Wb[1], Wb[2], b_t2c, b_t2t,
      b_c2t, b_c2c, Wh_t2c, Wh_t2t, Wh_c2t, Wh_c2c, NT, NC, nbT);

  // counting-sort CSR build
  int Emax = max(max(E_c2t, E_t2t), max(E_t2c, E_c2c));
  {
    dim3 g((Emax + EPB - 1) / EPB, 4);
    bucketCount_kernel<<<g, 256, 0, stream>>>(dst_c2t, E_c2t, dst_t2t, E_t2t,
                                              dst_t2c, E_t2c, dst_c2c, E_c2c,
                                              bcnt);
  }
  bucketScan_kernel<<<1, 256, 0, stream>>>(
      bcnt, bbase, off_c2t, NT, E_c2t, off_t2t, NT, E_t2t, off_t2c, NC, E_t2c,
      off_c2c, NC, E_c2c);
  {
    dim3 g((Emax + EPB - 1) / EPB, 4);
    bucketA_kernel<<<g, 256, 0, stream>>>(
        src_c2t, dst_c2t, E_c2t, tp_c2t, src_t2t, dst_t2t, E_t2t, tp_t2t,
        src_t2c, dst_t2c, E_t2c, tp_t2c, src_c2c, dst_c2c, E_c2c, tp_c2c,
        bbase, bcur);
  }
  {
    int nbmax = (max(NT, NC) + BSZ - 1) >> BSH;
    dim3 g(nbmax, 4);
    bucketFinal_kernel<<<g, 256, 0, stream>>>(
        tp_c2t, off_c2t, el_c2t, NT, tp_t2t, off_t2t, el_t2t, NT,
        tp_t2c, off_t2c, el_t2c, NC, tp_c2c, off_c2c, el_c2c, NC, bbase);
  }

  // h = 0.5*(meanA + meanB): NC first (big), then NT — separate dispatches
  // keep the gather working set at 51 MB each (merged 102 MB thrashed L2).
  aggregate_kernel<<<(NC + 3) / 4, 256, 0, stream>>>(
      Wh_t2c, off_t2c, el_t2c, Wh_c2c, off_c2c, el_c2c, h_col, NC);
  aggregate_kernel<<<(NT + 3) / 4, 256, 0, stream>>>(
      Wh_c2t, off_c2t, el_c2t, Wh_t2t, off_t2t, el_t2t, h_tab, NT);

  // out = lrelu(h @ W_h^T + b_h) + feat: both ntypes, flattened grid
  float* out_tab = (float*)d_out;
  float* out_col = out_tab + (size_t)NT * D;
  gemm1_dual<<<nbT + nbC, 256, 0, stream>>>(h_tab, h_col, Wb[4], b_h,
                                            feat_table, feat_column, out_tab,
                                            out_col, NT, NC, nbT);
}

// Round 12
// 531.715 us; speedup vs baseline: 1.0837x; 1.0837x over previous
//
#include <hip/hip_runtime.h>

#define D 256
#define SLOPE 0.01f

// bucket scatter params
#define BSH 9
#define BSZ 512
#define NBMAX 160
#define EPB 8192

typedef __attribute__((ext_vector_type(8))) short bf16x8;
typedef __attribute__((ext_vector_type(4))) float f32x4;

__device__ __forceinline__ float bfbits2f(unsigned int hi) {
  return __builtin_bit_cast(float, hi);
}
__device__ __forceinline__ unsigned short f2bf(float f) {
  unsigned u = __builtin_bit_cast(unsigned, f);
  u += 0x7fffu + ((u >> 16) & 1u);
  return (unsigned short)(u >> 16);
}
__device__ __forceinline__ float lrelu(float x) {
  return (x >= 0.f) ? x : SLOPE * x;
}

__device__ __forceinline__ void gld_lds16(const void* g, void* l) {
  __builtin_amdgcn_global_load_lds(
      (const __attribute__((address_space(1))) unsigned int*)g,
      (__attribute__((address_space(3))) unsigned int*)l, 16, 0, 0);
}

// batched weight cast: 5 weights of D*D floats each
__global__ void cast5_kernel(const float* w0, const float* w1, const float* w2,
                             const float* w3, const float* w4,
                             unsigned short* o0, unsigned short* o1,
                             unsigned short* o2, unsigned short* o3,
                             unsigned short* o4) {
  int a = blockIdx.y;
  const float* in = a == 0 ? w0 : a == 1 ? w1 : a == 2 ? w2 : a == 3 ? w3 : w4;
  unsigned short* out = a == 0 ? o0 : a == 1 ? o1 : a == 2 ? o2 : a == 3 ? o3 : o4;
  int i = blockIdx.x * blockDim.x + threadIdx.x;  // over D*D/4
  float4 v = ((const float4*)in)[i];
  ushort4 o;
  o.x = f2bf(v.x); o.y = f2bf(v.y); o.z = f2bf(v.z); o.w = f2bf(v.w);
  ((ushort4*)out)[i] = o;
}

// ---------------- GEMM building blocks ----------------
// Round-12: REVERT to round-10 structure (best, 534us; round-11's 32-col
// occupancy experiment regressed via L2 thrash: FETCH 53->136MB). One fix:
// stage_A_f32 split into {issue ALL loads} then {convert + ds_write} (T14)
// so staging costs ~1 HBM round trip instead of 8 serialized.

// bf16 source staging via global_load_lds (used by gemm1).
__device__ __forceinline__ void stage_A(unsigned short* Xs,
                                        const unsigned short* __restrict__ A,
                                        int M, int mblk) {
  const int t = threadIdx.x;
  const int w = t >> 6, lane = t & 63;
#pragma unroll
  for (int i = 0; i < 8; i++) {
    const int m = (i * 4 + w) * 2 + (lane >> 5);
    int row = mblk + m;
    if (row > M - 1) row = M - 1;
    const int jsrc = (lane & 31) ^ (m & 7);
    gld_lds16(A + (size_t)row * D + jsrc * 8, &Xs[(i * 4 + w) * 512]);
  }
}

// fp32 source staging (fused cast), load/write SPLIT: phase 1 issues all
// 16 float4 loads (64 transient VGPRs, before wf is live); phase 2
// converts + writes 16B swizzled chunks. LDS layout unchanged:
// chunk (m,j) -> LDS chunk m*32 + (j^(m&7)).
__device__ __forceinline__ void stage_A_f32(unsigned short* Xs,
                                            const float* __restrict__ A,
                                            int M, int mblk) {
  const int t = threadIdx.x;
  float4 v0[8], v1[8];
  int cds[8];
#pragma unroll
  for (int c = 0; c < 8; c++) {
    const int chunk = c * 256 + t;
    const int m = chunk >> 5, jg = chunk & 31;
    int row = mblk + m;
    if (row > M - 1) row = M - 1;
    const float* gp = A + (size_t)row * D + jg * 8;
    v0[c] = *(const float4*)gp;
    v1[c] = *(const float4*)(gp + 4);
    cds[c] = m * 32 + (jg ^ (m & 7));
  }
#pragma unroll
  for (int c = 0; c < 8; c++) {
    uint4 pk;
    pk.x = (unsigned)f2bf(v0[c].x) | ((unsigned)f2bf(v0[c].y) << 16);
    pk.y = (unsigned)f2bf(v0[c].z) | ((unsigned)f2bf(v0[c].w) << 16);
    pk.z = (unsigned)f2bf(v1[c].x) | ((unsigned)f2bf(v1[c].y) << 16);
    pk.w = (unsigned)f2bf(v1[c].z) | ((unsigned)f2bf(v1[c].w) << 16);
    *(uint4*)&Xs[cds[c] * 8] = pk;
  }
}

// One 64-row x 256-col product off an already-staged (or in-flight) A tile.
// SYNC=true: drain staging + barrier AFTER the W loads are issued.
template <int MODE, bool SYNC>
__device__ __forceinline__ void gemm_compute(
    const unsigned short* Xs, const unsigned short* __restrict__ B,
    const float* __restrict__ bias, const float* __restrict__ residual,
    unsigned short* __restrict__ outb, float* __restrict__ outf, int M,
    int mblk) {
  const int t = threadIdx.x;
  const int w = t >> 6, lane = t & 63;
  const int fr = lane & 15;
  const int jb = lane >> 4;

  bf16x8 wf[4][8];
  {
    const unsigned short* wp = B + (size_t)(w * 64 + fr) * D + jb * 8;
#pragma unroll
    for (int nt = 0; nt < 4; nt++)
#pragma unroll
      for (int k0 = 0; k0 < 8; k0++)
        wf[nt][k0] = *(const bf16x8*)(wp + nt * 16 * D + k0 * 32);
  }

  if (SYNC) {
    asm volatile("s_waitcnt vmcnt(0)" ::: "memory");
    __syncthreads();
  }

  f32x4 acc[4][4];
#pragma unroll
  for (int i = 0; i < 4; i++)
#pragma unroll
    for (int j = 0; j < 4; j++) acc[i][j] = (f32x4){0.f, 0.f, 0.f, 0.f};

  const int r = fr & 7;
#pragma unroll
  for (int k0 = 0; k0 < 8; k0++) {
    bf16x8 xf[4];
#pragma unroll
    for (int mt = 0; mt < 4; mt++) {
      const int ml = mt * 16 + fr;
      xf[mt] = *(const bf16x8*)&Xs[ml * 256 + (((k0 * 4 + jb) ^ r) * 8)];
    }
#pragma unroll
    for (int mt = 0; mt < 4; mt++)
#pragma unroll
      for (int nt = 0; nt < 4; nt++)
        acc[mt][nt] = __builtin_amdgcn_mfma_f32_16x16x32_bf16(
            wf[nt][k0], xf[mt], acc[mt][nt], 0, 0, 0);
  }

  const int n0 = w * 64 + jb * 4;
  float4 bv[4];
#pragma unroll
  for (int nt = 0; nt < 4; nt++) bv[nt] = *(const float4*)&bias[n0 + nt * 16];

#pragma unroll
  for (int mt = 0; mt < 4; mt++) {
    const int m = mblk + mt * 16 + fr;
    if (m < M) {
      if (MODE == 1) {
        float4 rv[4];
#pragma unroll
        for (int nt = 0; nt < 4; nt++)
          rv[nt] = *(const float4*)&residual[(size_t)m * D + n0 + nt * 16];
#pragma unroll
        for (int nt = 0; nt < 4; nt++) {
          float4 o;
          o.x = lrelu(acc[mt][nt][0] + bv[nt].x) + rv[nt].x;
          o.y = lrelu(acc[mt][nt][1] + bv[nt].y) + rv[nt].y;
          o.z = lrelu(acc[mt][nt][2] + bv[nt].z) + rv[nt].z;
          o.w = lrelu(acc[mt][nt][3] + bv[nt].w) + rv[nt].w;
          *(float4*)&outf[(size_t)m * D + n0 + nt * 16] = o;
        }
      } else {
#pragma unroll
        for (int nt = 0; nt < 4; nt++) {
          ushort4 o;
          o.x = f2bf(lrelu(acc[mt][nt][0] + bv[nt].x));
          o.y = f2bf(lrelu(acc[mt][nt][1] + bv[nt].y));
          o.z = f2bf(lrelu(acc[mt][nt][2] + bv[nt].z));
          o.w = f2bf(lrelu(acc[mt][nt][3] + bv[nt].w));
          *(ushort4*)&outb[(size_t)m * D + n0 + nt * 16] = o;
        }
      }
    }
  }
}

// Wh = lrelu(feat@W^T+b) for BOTH etypes of one ntype per block, reading
// fp32 feat directly (fused cast). y: 0=table, 1=column.
__global__ __launch_bounds__(256, 2) void gemm0_pair(
    const float* __restrict__ A0, const float* __restrict__ A1,
    const unsigned short* __restrict__ B00, const unsigned short* __restrict__ B01,
    const unsigned short* __restrict__ B10, const unsigned short* __restrict__ B11,
    const float* b00, const float* b01, const float* b10, const float* b11,
    unsigned short* o00, unsigned short* o01, unsigned short* o10,
    unsigned short* o11, int M0, int M1) {
  __shared__ __attribute__((aligned(16))) unsigned short Xs[64 * 256];
  int a = blockIdx.y;
  const float* A = a ? A1 : A0;
  int M = a ? M1 : M0;
  int mblk = blockIdx.x * 64;
  if (mblk >= M) return;
  stage_A_f32(Xs, A, M, mblk);  // loads issued first, writes late (T14)
  __syncthreads();
  gemm_compute<0, false>(Xs, a ? B10 : B00, a ? b10 : b00, nullptr,
                         a ? o10 : o00, nullptr, M, mblk);
  gemm_compute<0, false>(Xs, a ? B11 : B01, a ? b11 : b01, nullptr,
                         a ? o11 : o01, nullptr, M, mblk);
}

// both final GEMMs (out = lrelu(h@Wh^T+bh)+feat) in ONE dispatch.
__global__ __launch_bounds__(256, 2) void gemm1_dual(
    const unsigned short* __restrict__ A0, const unsigned short* __restrict__ A1,
    const unsigned short* __restrict__ Bw, const float* bh,
    const float* __restrict__ r0, const float* __restrict__ r1,
    float* __restrict__ o0, float* __restrict__ o1, int M0, int M1) {
  __shared__ __attribute__((aligned(16))) unsigned short Xs[64 * 256];
  int a = blockIdx.y;
  const unsigned short* A = a ? A1 : A0;
  int M = a ? M1 : M0;
  int mblk = blockIdx.x * 64;
  if (mblk >= M) return;
  stage_A(Xs, A, M, mblk);
  gemm_compute<1, true>(Xs, Bw, bh, a ? r1 : r0, nullptr, a ? o1 : o0, M, mblk);
}

// ---------------- counting-sort CSR build ----------------
// Pass 1: per-block LDS histogram over 512-dst buckets.
__global__ __launch_bounds__(256) void bucketCount_kernel(
    const int* d0, int n0, const int* d1, int n1, const int* d2, int n2,
    const int* d3, int n3, int* __restrict__ bcnt) {
  int a = blockIdx.y;
  const int* dst = a == 0 ? d0 : a == 1 ? d1 : a == 2 ? d2 : d3;
  int n = a == 0 ? n0 : a == 1 ? n1 : a == 2 ? n2 : n3;
  int blk = blockIdx.x;
  if (blk * EPB >= n) return;
  int t = threadIdx.x;
  __shared__ int cnt[NBMAX];
  if (t < NBMAX) cnt[t] = 0;
  __syncthreads();
  int i0 = blk * EPB + t;
#pragma unroll 4
  for (int it = 0; it < EPB / 256; it++) {
    int i = i0 + it * 256;
    if (i < n) atomicAdd(&cnt[dst[i] >> BSH], 1);
  }
  __syncthreads();
  if (t < NBMAX && cnt[t]) atomicAdd(&bcnt[a * NBMAX + t], cnt[t]);
}

// Pass 2: one block scans 4x160 bucket totals -> bbase; writes off[nn]=E.
__global__ __launch_bounds__(256) void bucketScan_kernel(
    const int* __restrict__ bcnt, int* __restrict__ bbase,
    int* o0, int n0, int e0, int* o1, int n1, int e1,
    int* o2, int n2, int e2, int* o3, int n3, int e3) {
  __shared__ int s[256];
  int t = threadIdx.x;
  for (int a = 0; a < 4; a++) {
    int v = (t < NBMAX) ? bcnt[a * NBMAX + t] : 0;
    s[t] = v;
    __syncthreads();
    for (int off = 1; off < 256; off <<= 1) {
      int u = (t >= off) ? s[t - off] : 0;
      __syncthreads();
      s[t] += u;
      __syncthreads();
    }
    if (t < NBMAX)
      bbase[a * (NBMAX + 1) + t] = s[t] - v;
    else if (t == NBMAX)
      bbase[a * (NBMAX + 1) + NBMAX] = s[NBMAX - 1];
    __syncthreads();
  }
  if (t == 0) { o0[n0] = e0; o1[n1] = e1; o2[n2] = e2; o3[n3] = e3; }
}

// Pass 3: scatter edges into bucket-grouped temp (packed src<<9|dstlow).
__global__ __launch_bounds__(256) void bucketA_kernel(
    const int* s0, const int* d0, int n0, unsigned* t0,
    const int* s1, const int* d1, int n1, unsigned* t1,
    const int* s2, const int* d2, int n2, unsigned* t2,
    const int* s3, const int* d3, int n3, unsigned* t3,
    const int* __restrict__ bbase, int* __restrict__ bcur) {
  int a = blockIdx.y;
  const int* src = a == 0 ? s0 : a == 1 ? s1 : a == 2 ? s2 : s3;
  const int* dst = a == 0 ? d0 : a == 1 ? d1 : a == 2 ? d2 : d3;
  int n = a == 0 ? n0 : a == 1 ? n1 : a == 2 ? n2 : n3;
  unsigned* temp = a == 0 ? t0 : a == 1 ? t1 : a == 2 ? t2 : t3;

  int blk = blockIdx.x;
  if (blk * EPB >= n) return;
  int t = threadIdx.x;
  __shared__ int cnt[NBMAX];
  __shared__ int lbase[NBMAX];
  if (t < NBMAX) cnt[t] = 0;
  __syncthreads();

  int i0 = blk * EPB + t;
#pragma unroll 4
  for (int it = 0; it < EPB / 256; it++) {
    int i = i0 + it * 256;
    if (i < n) atomicAdd(&cnt[dst[i] >> BSH], 1);
  }
  __syncthreads();
  if (t < NBMAX) {
    int c = cnt[t];
    int g = c ? atomicAdd(&bcur[a * NBMAX + t], c) : 0;
    lbase[t] = g + bbase[a * (NBMAX + 1) + t];
    cnt[t] = 0;
  }
  __syncthreads();
#pragma unroll 4
  for (int it = 0; it < EPB / 256; it++) {
    int i = i0 + it * 256;
    if (i < n) {
      int d = dst[i];
      int b = d >> BSH;
      int rk = atomicAdd(&cnt[b], 1);
      temp[lbase[b] + rk] = ((unsigned)src[i] << BSH) | (unsigned)(d & (BSZ - 1));
    }
  }
}

// Pass 4: one block per bucket: LDS count+scan of 512 dst slots, write
// off[node] (sequential), scatter src into elist (L2-local window).
__global__ __launch_bounds__(256) void bucketFinal_kernel(
    const unsigned* t0, int* o0, int* e0, int m0,
    const unsigned* t1, int* o1, int* e1, int m1,
    const unsigned* t2, int* o2, int* e2, int m2,
    const unsigned* t3, int* o3, int* e3, int m3,
    const int* __restrict__ bbase) {
  int a = blockIdx.y;
  const unsigned* temp = a == 0 ? t0 : a == 1 ? t1 : a == 2 ? t2 : t3;
  int* offs = a == 0 ? o0 : a == 1 ? o1 : a == 2 ? o2 : o3;
  int* elist = a == 0 ? e0 : a == 1 ? e1 : a == 2 ? e2 : e3;
  int nn = a == 0 ? m0 : a == 1 ? m1 : a == 2 ? m2 : m3;

  int nb = (nn + BSZ - 1) >> BSH;
  int b = blockIdx.x;
  if (b >= nb) return;
  int lo = bbase[a * (NBMAX + 1) + b];
  int hi = bbase[a * (NBMAX + 1) + b + 1];
  int t = threadIdx.x;

  __shared__ int cnt[BSZ];
  __shared__ int psum[BSZ];
  __shared__ int sm[256];
  cnt[t] = 0; cnt[t + 256] = 0;
  __syncthreads();
  for (int i = lo + t; i < hi; i += 256)
    atomicAdd(&cnt[temp[i] & (BSZ - 1)], 1);
  __syncthreads();
  int c0 = cnt[2 * t], c1 = cnt[2 * t + 1];
  int s = c0 + c1;
  sm[t] = s;
  __syncthreads();
  for (int off = 1; off < 256; off <<= 1) {
    int u = (t >= off) ? sm[t - off] : 0;
    __syncthreads();
    sm[t] += u;
    __syncthreads();
  }
  int ex = sm[t] - s;
  psum[2 * t] = ex;
  psum[2 * t + 1] = ex + c0;
  cnt[2 * t] = 0; cnt[2 * t + 1] = 0;   // reuse as cursors
  __syncthreads();

  int node0 = b << BSH;
  if (node0 + 2 * t < nn) offs[node0 + 2 * t] = lo + psum[2 * t];
  if (node0 + 2 * t + 1 < nn) offs[node0 + 2 * t + 1] = lo + psum[2 * t + 1];

  for (int i = lo + t; i < hi; i += 256) {
    unsigned v = temp[i];
    int d = v & (BSZ - 1);
    int rk = atomicAdd(&cnt[d], 1);
    elist[lo + psum[d] + rk] = (int)(v >> BSH);
  }
}

// ---------------- aggregation: one wave per dst node, two etypes fused ------
__device__ __forceinline__ void add8(float* acc, uint4 p) {
  acc[0] += bfbits2f(p.x << 16);
  acc[1] += bfbits2f(p.x & 0xffff0000u);
  acc[2] += bfbits2f(p.y << 16);
  acc[3] += bfbits2f(p.y & 0xffff0000u);
  acc[4] += bfbits2f(p.z << 16);
  acc[5] += bfbits2f(p.z & 0xffff0000u);
  acc[6] += bfbits2f(p.w << 16);
  acc[7] += bfbits2f(p.w & 0xffff0000u);
}

__global__ __launch_bounds__(256) void aggregate_kernel(
    const unsigned short* __restrict__ WhA, const int* __restrict__ offsA,
    const int* __restrict__ elistA, const unsigned short* __restrict__ WhB,
    const int* __restrict__ offsB, const int* __restrict__ elistB,
    unsigned short* __restrict__ hout, int n) {
  int wave = (blockIdx.x * 256 + threadIdx.x) >> 6;
  int lane = threadIdx.x & 63;
  if (wave >= n) return;
  int half = lane >> 5;
  int l32 = lane & 31;
  size_t coff = (size_t)l32 * 8;  // channel offset in shorts

  float accA[8] = {0, 0, 0, 0, 0, 0, 0, 0};
  float accB[8] = {0, 0, 0, 0, 0, 0, 0, 0};
  float scA, scB;

  {
    int e0 = offsA[wave], e1 = offsA[wave + 1];
    scA = 0.5f / fmaxf((float)(e1 - e0), 1.0f);
    int e = e0;
    for (; e + 8 <= e1; e += 8) {
      int s0 = elistA[e + half];
      int s1 = elistA[e + 2 + half];
      int s2 = elistA[e + 4 + half];
      int s3 = elistA[e + 6 + half];
      uint4 p0 = *(const uint4*)(WhA + (size_t)s0 * D + coff);
      uint4 p1 = *(const uint4*)(WhA + (size_t)s1 * D + coff);
      uint4 p2 = *(const uint4*)(WhA + (size_t)s2 * D + coff);
      uint4 p3 = *(const uint4*)(WhA + (size_t)s3 * D + coff);
      add8(accA, p0); add8(accA, p1); add8(accA, p2); add8(accA, p3);
    }
    for (; e + 2 <= e1; e += 2) {
      int s0 = elistA[e + half];
      uint4 p0 = *(const uint4*)(WhA + (size_t)s0 * D + coff);
      add8(accA, p0);
    }
    if (e < e1 && half == 0) {
      int s0 = elistA[e];
      uint4 p0 = *(const uint4*)(WhA + (size_t)s0 * D + coff);
      add8(accA, p0);
    }
  }
  {
    int e0 = offsB[wave], e1 = offsB[wave + 1];
    scB = 0.5f / fmaxf((float)(e1 - e0), 1.0f);
    int e = e0;
    for (; e + 8 <= e1; e += 8) {
      int s0 = elistB[e + half];
      int s1 = elistB[e + 2 + half];
      int s2 = elistB[e + 4 + half];
      int s3 = elistB[e + 6 + half];
      uint4 p0 = *(const uint4*)(WhB + (size_t)s0 * D + coff);
      uint4 p1 = *(const uint4*)(WhB + (size_t)s1 * D + coff);
      uint4 p2 = *(const uint4*)(WhB + (size_t)s2 * D + coff);
      uint4 p3 = *(const uint4*)(WhB + (size_t)s3 * D + coff);
      add8(accB, p0); add8(accB, p1); add8(accB, p2); add8(accB, p3);
    }
    for (; e + 2 <= e1; e += 2) {
      int s0 = elistB[e + half];
      uint4 p0 = *(const uint4*)(WhB + (size_t)s0 * D + coff);
      add8(accB, p0);
    }
    if (e < e1 && half == 0) {
      int s0 = elistB[e];
      uint4 p0 = *(const uint4*)(WhB + (size_t)s0 * D + coff);
      add8(accB, p0);
    }
  }

  float h[8];
#pragma unroll
  for (int j = 0; j < 8; j++) {
    h[j] = accA[j] * scA + accB[j] * scB;
    h[j] += __shfl_down(h[j], 32);
  }
  if (half == 0) {
    uint4 o;
    o.x = (unsigned)f2bf(h[0]) | ((unsigned)f2bf(h[1]) << 16);
    o.y = (unsigned)f2bf(h[2]) | ((unsigned)f2bf(h[3]) << 16);
    o.z = (unsigned)f2bf(h[4]) | ((unsigned)f2bf(h[5]) << 16);
    o.w = (unsigned)f2bf(h[6]) | ((unsigned)f2bf(h[7]) << 16);
    *(uint4*)(hout + (size_t)wave * D + coff) = o;
  }
}

// ---------------- launch ----------------
extern "C" void kernel_launch(void* const* d_in, const int* in_sizes, int n_in,
                              void* d_out, int out_size, void* d_ws,
                              size_t ws_size, hipStream_t stream) {
  const float* feat_table = (const float*)d_in[0];
  const float* feat_column = (const float*)d_in[1];
  const float* Wsrc[5] = {(const float*)d_in[2], (const float*)d_in[4],
                          (const float*)d_in[6], (const float*)d_in[8],
                          (const float*)d_in[10]};
  const float* b_t2c = (const float*)d_in[3];
  const float* b_c2t = (const float*)d_in[5];
  const float* b_c2c = (const float*)d_in[7];
  const float* b_t2t = (const float*)d_in[9];
  const float* b_h = (const float*)d_in[11];
  const int* src_t2c = (const int*)d_in[12];
  const int* dst_t2c = (const int*)d_in[13];
  const int* src_c2t = (const int*)d_in[14];
  const int* dst_c2t = (const int*)d_in[15];
  const int* src_c2c = (const int*)d_in[16];
  const int* dst_c2c = (const int*)d_in[17];
  const int* src_t2t = (const int*)d_in[18];
  const int* dst_t2t = (const int*)d_in[19];

  const int NT = in_sizes[0] / D;
  const int NC = in_sizes[1] / D;
  const int E_t2c = in_sizes[12], E_c2t = in_sizes[14];
  const int E_c2c = in_sizes[16], E_t2t = in_sizes[18];

  char* ws = (char*)d_ws;
  size_t cur = 0;
  auto alloc = [&](size_t bytes) -> void* {
    void* p = ws + cur;
    cur += (bytes + 255) & ~(size_t)255;
    return p;
  };
  unsigned short* Wb[5];
  for (int i = 0; i < 5; i++) Wb[i] = (unsigned short*)alloc((size_t)D * D * 2);
  // scratch region: bucket temp (bucketA->bucketFinal), then h_tab/h_col
  // (aggregate->gemm1). Sized for the larger of the two uses.
  size_t scratchA = sizeof(unsigned) * ((size_t)E_c2t + E_t2t + E_t2c + E_c2c);
  size_t scratchB = (size_t)(NT + NC) * D * 2;
  unsigned short* scr = (unsigned short*)alloc(scratchA > scratchB ? scratchA
                                                                   : scratchB);
  unsigned short* Wh_t2c = (unsigned short*)alloc((size_t)NT * D * 2);
  unsigned short* Wh_c2t = (unsigned short*)alloc((size_t)NC * D * 2);
  unsigned short* Wh_c2c = (unsigned short*)alloc((size_t)NC * D * 2);
  unsigned short* Wh_t2t = (unsigned short*)alloc((size_t)NT * D * 2);
  // bucket counters (zeroed): bcnt[4][160] + bcur[4][160]
  int* bcnt = (int*)alloc(sizeof(int) * 2 * 4 * NBMAX);
  int* bcur = bcnt + 4 * NBMAX;
  int* bbase = (int*)alloc(sizeof(int) * 4 * (NBMAX + 1));
  int* off_c2t = (int*)alloc(sizeof(int) * (NT + 1));
  int* off_t2t = (int*)alloc(sizeof(int) * (NT + 1));
  int* off_t2c = (int*)alloc(sizeof(int) * (NC + 1));
  int* off_c2c = (int*)alloc(sizeof(int) * (NC + 1));
  int* el_c2t = (int*)alloc(sizeof(int) * E_c2t);
  int* el_t2t = (int*)alloc(sizeof(int) * E_t2t);
  int* el_t2c = (int*)alloc(sizeof(int) * E_t2c);
  int* el_c2c = (int*)alloc(sizeof(int) * E_c2c);

  // scratch region aliases (lifetimes disjoint; stream serializes)
  unsigned* tp_c2t = (unsigned*)scr;
  unsigned* tp_t2t = tp_c2t + E_c2t;
  unsigned* tp_t2c = tp_t2t + E_t2t;
  unsigned* tp_c2c = tp_t2c + E_t2c;
  unsigned short* h_tab = scr;
  unsigned short* h_col = scr + (size_t)NT * D;

  hipMemsetAsync(bcnt, 0, sizeof(int) * 2 * 4 * NBMAX, stream);

  // weight casts
  {
    dim3 g((D * D / 4 + 255) / 256, 5);
    cast5_kernel<<<g, 256, 0, stream>>>(Wsrc[0], Wsrc[1], Wsrc[2], Wsrc[3],
                                        Wsrc[4], Wb[0], Wb[1], Wb[2], Wb[3],
                                        Wb[4]);
  }

  // Wh = lrelu(feat @ W^T + b): fp32 feat read directly (fused cast),
  // both etypes per ntype off one staged A tile.
  {
    dim3 g((max(NT, NC) + 63) / 64, 2);
    gemm0_pair<<<g, 256, 0, stream>>>(
        feat_table, feat_column, Wb[0], Wb[3], Wb[1], Wb[2], b_t2c, b_t2t,
        b_c2t, b_c2c, Wh_t2c, Wh_t2t, Wh_c2t, Wh_c2c, NT, NC);
  }

  // counting-sort CSR build
  int Emax = max(max(E_c2t, E_t2t), max(E_t2c, E_c2c));
  {
    dim3 g((Emax + EPB - 1) / EPB, 4);
    bucketCount_kernel<<<g, 256, 0, stream>>>(dst_c2t, E_c2t, dst_t2t, E_t2t,
                                              dst_t2c, E_t2c, dst_c2c, E_c2c,
                                              bcnt);
  }
  bucketScan_kernel<<<1, 256, 0, stream>>>(
      bcnt, bbase, off_c2t, NT, E_c2t, off_t2t, NT, E_t2t, off_t2c, NC, E_t2c,
      off_c2c, NC, E_c2c);
  {
    dim3 g((Emax + EPB - 1) / EPB, 4);
    bucketA_kernel<<<g, 256, 0, stream>>>(
        src_c2t, dst_c2t, E_c2t, tp_c2t, src_t2t, dst_t2t, E_t2t, tp_t2t,
        src_t2c, dst_t2c, E_t2c, tp_t2c, src_c2c, dst_c2c, E_c2c, tp_c2c,
        bbase, bcur);
  }
  {
    int nbmax = (max(NT, NC) + BSZ - 1) >> BSH;
    dim3 g(nbmax, 4);
    bucketFinal_kernel<<<g, 256, 0, stream>>>(
        tp_c2t, off_c2t, el_c2t, NT, tp_t2t, off_t2t, el_t2t, NT,
        tp_t2c, off_t2c, el_t2c, NC, tp_c2c, off_c2c, el_c2c, NC, bbase);
  }

  // h = 0.5*(meanA + meanB): NC first (big), then NT — separate dispatches
  // keep the gather working set at 51 MB each (merged 102 MB thrashed L2).
  aggregate_kernel<<<(NC + 3) / 4, 256, 0, stream>>>(
      Wh_t2c, off_t2c, el_t2c, Wh_c2c, off_c2c, el_c2c, h_col, NC);
  aggregate_kernel<<<(NT + 3) / 4, 256, 0, stream>>>(
      Wh_c2t, off_c2t, el_c2t, Wh_t2t, off_t2t, el_t2t, h_tab, NT);

  // out = lrelu(h @ W_h^T + b_h) + feat: both ntypes in one dispatch
  float* out_tab = (float*)d_out;
  float* out_col = out_tab + (size_t)NT * D;
  {
    dim3 g((max(NT, NC) + 63) / 64, 2);
    gemm1_dual<<<g, 256, 0, stream>>>(h_tab, h_col, Wb[4], b_h, feat_table,
                                      feat_column, out_tab, out_col, NT, NC);
  }
}

// Round 13
// 517.506 us; speedup vs baseline: 1.1134x; 1.0275x over previous
//
#include <hip/hip_runtime.h>

#define D 256
#define SLOPE 0.01f

// bucket scatter params
#define BSH 9
#define BSZ 512
#define NBMAX 160
#define EPB 8192

typedef __attribute__((ext_vector_type(8))) short bf16x8;
typedef __attribute__((ext_vector_type(4))) float f32x4;

__device__ __forceinline__ float bfbits2f(unsigned int hi) {
  return __builtin_bit_cast(float, hi);
}
__device__ __forceinline__ unsigned short f2bf(float f) {
  unsigned u = __builtin_bit_cast(unsigned, f);
  u += 0x7fffu + ((u >> 16) & 1u);
  return (unsigned short)(u >> 16);
}
__device__ __forceinline__ float lrelu(float x) {
  return (x >= 0.f) ? x : SLOPE * x;
}

__device__ __forceinline__ void gld_lds16(const void* g, void* l) {
  __builtin_amdgcn_global_load_lds(
      (const __attribute__((address_space(1))) unsigned int*)g,
      (__attribute__((address_space(3))) unsigned int*)l, 16, 0, 0);
}

// batched weight cast: 5 weights of D*D floats each
__global__ void cast5_kernel(const float* w0, const float* w1, const float* w2,
                             const float* w3, const float* w4,
                             unsigned short* o0, unsigned short* o1,
                             unsigned short* o2, unsigned short* o3,
                             unsigned short* o4) {
  int a = blockIdx.y;
  const float* in = a == 0 ? w0 : a == 1 ? w1 : a == 2 ? w2 : a == 3 ? w3 : w4;
  unsigned short* out = a == 0 ? o0 : a == 1 ? o1 : a == 2 ? o2 : a == 3 ? o3 : o4;
  int i = blockIdx.x * blockDim.x + threadIdx.x;  // over D*D/4
  float4 v = ((const float4*)in)[i];
  ushort4 o;
  o.x = f2bf(v.x); o.y = f2bf(v.y); o.z = f2bf(v.z); o.w = f2bf(v.w);
  ((ushort4*)out)[i] = o;
}

// ---------------- GEMM building blocks ----------------
// Round-13: gemm0 = QUAD structure (1 etype/block, r7's 82us shape) +
// FUSED fp32->bf16 staging (r10's cast elimination). Pair+fused cost +30us
// (serial chain too long at 1.5 waves/SIMD); quad halves the per-block
// chain and doubles block count -> cross-block overlap. fp32 feat re-read
// per etype is L3-resident (r7: FETCH 52MB), so no HBM cost.

// bf16 source staging via global_load_lds (used by gemm1).
__device__ __forceinline__ void stage_A(unsigned short* Xs,
                                        const unsigned short* __restrict__ A,
                                        int M, int mblk) {
  const int t = threadIdx.x;
  const int w = t >> 6, lane = t & 63;
#pragma unroll
  for (int i = 0; i < 8; i++) {
    const int m = (i * 4 + w) * 2 + (lane >> 5);
    int row = mblk + m;
    if (row > M - 1) row = M - 1;
    const int jsrc = (lane & 31) ^ (m & 7);
    gld_lds16(A + (size_t)row * D + jsrc * 8, &Xs[(i * 4 + w) * 512]);
  }
}

// fp32 source staging (fused cast), load/write SPLIT (T14): phase 1 issues
// all 16 float4 loads; phase 2 converts + writes 16B swizzled chunks.
// LDS layout: chunk (m,j) -> LDS chunk m*32 + (j^(m&7)).
__device__ __forceinline__ void stage_A_f32(unsigned short* Xs,
                                            const float* __restrict__ A,
                                            int M, int mblk) {
  const int t = threadIdx.x;
  float4 v0[8], v1[8];
  int cds[8];
#pragma unroll
  for (int c = 0; c < 8; c++) {
    const int chunk = c * 256 + t;
    const int m = chunk >> 5, jg = chunk & 31;
    int row = mblk + m;
    if (row > M - 1) row = M - 1;
    const float* gp = A + (size_t)row * D + jg * 8;
    v0[c] = *(const float4*)gp;
    v1[c] = *(const float4*)(gp + 4);
    cds[c] = m * 32 + (jg ^ (m & 7));
  }
#pragma unroll
  for (int c = 0; c < 8; c++) {
    uint4 pk;
    pk.x = (unsigned)f2bf(v0[c].x) | ((unsigned)f2bf(v0[c].y) << 16);
    pk.y = (unsigned)f2bf(v0[c].z) | ((unsigned)f2bf(v0[c].w) << 16);
    pk.z = (unsigned)f2bf(v1[c].x) | ((unsigned)f2bf(v1[c].y) << 16);
    pk.w = (unsigned)f2bf(v1[c].z) | ((unsigned)f2bf(v1[c].w) << 16);
    *(uint4*)&Xs[cds[c] * 8] = pk;
  }
}

// One 64-row x 256-col product off an already-staged (or in-flight) A tile.
// SYNC=true: drain staging + barrier AFTER the W loads are issued.
template <int MODE, bool SYNC>
__device__ __forceinline__ void gemm_compute(
    const unsigned short* Xs, const unsigned short* __restrict__ B,
    const float* __restrict__ bias, const float* __restrict__ residual,
    unsigned short* __restrict__ outb, float* __restrict__ outf, int M,
    int mblk) {
  const int t = threadIdx.x;
  const int w = t >> 6, lane = t & 63;
  const int fr = lane & 15;
  const int jb = lane >> 4;

  bf16x8 wf[4][8];
  {
    const unsigned short* wp = B + (size_t)(w * 64 + fr) * D + jb * 8;
#pragma unroll
    for (int nt = 0; nt < 4; nt++)
#pragma unroll
      for (int k0 = 0; k0 < 8; k0++)
        wf[nt][k0] = *(const bf16x8*)(wp + nt * 16 * D + k0 * 32);
  }

  if (SYNC) {
    asm volatile("s_waitcnt vmcnt(0)" ::: "memory");
    __syncthreads();
  }

  f32x4 acc[4][4];
#pragma unroll
  for (int i = 0; i < 4; i++)
#pragma unroll
    for (int j = 0; j < 4; j++) acc[i][j] = (f32x4){0.f, 0.f, 0.f, 0.f};

  const int r = fr & 7;
#pragma unroll
  for (int k0 = 0; k0 < 8; k0++) {
    bf16x8 xf[4];
#pragma unroll
    for (int mt = 0; mt < 4; mt++) {
      const int ml = mt * 16 + fr;
      xf[mt] = *(const bf16x8*)&Xs[ml * 256 + (((k0 * 4 + jb) ^ r) * 8)];
    }
#pragma unroll
    for (int mt = 0; mt < 4; mt++)
#pragma unroll
      for (int nt = 0; nt < 4; nt++)
        acc[mt][nt] = __builtin_amdgcn_mfma_f32_16x16x32_bf16(
            wf[nt][k0], xf[mt], acc[mt][nt], 0, 0, 0);
  }

  const int n0 = w * 64 + jb * 4;
  float4 bv[4];
#pragma unroll
  for (int nt = 0; nt < 4; nt++) bv[nt] = *(const float4*)&bias[n0 + nt * 16];

#pragma unroll
  for (int mt = 0; mt < 4; mt++) {
    const int m = mblk + mt * 16 + fr;
    if (m < M) {
      if (MODE == 1) {
        float4 rv[4];
#pragma unroll
        for (int nt = 0; nt < 4; nt++)
          rv[nt] = *(const float4*)&residual[(size_t)m * D + n0 + nt * 16];
#pragma unroll
        for (int nt = 0; nt < 4; nt++) {
          float4 o;
          o.x = lrelu(acc[mt][nt][0] + bv[nt].x) + rv[nt].x;
          o.y = lrelu(acc[mt][nt][1] + bv[nt].y) + rv[nt].y;
          o.z = lrelu(acc[mt][nt][2] + bv[nt].z) + rv[nt].z;
          o.w = lrelu(acc[mt][nt][3] + bv[nt].w) + rv[nt].w;
          *(float4*)&outf[(size_t)m * D + n0 + nt * 16] = o;
        }
      } else {
#pragma unroll
        for (int nt = 0; nt < 4; nt++) {
          ushort4 o;
          o.x = f2bf(lrelu(acc[mt][nt][0] + bv[nt].x));
          o.y = f2bf(lrelu(acc[mt][nt][1] + bv[nt].y));
          o.z = f2bf(lrelu(acc[mt][nt][2] + bv[nt].z));
          o.w = f2bf(lrelu(acc[mt][nt][3] + bv[nt].w));
          *(ushort4*)&outb[(size_t)m * D + n0 + nt * 16] = o;
        }
      }
    }
  }
}

// Wh = lrelu(feat@W^T+b), ONE etype per block (quad), fused fp32 staging.
// y: 0=t2c, 1=t2t (table); 2=c2t, 3=c2c (column).
__global__ __launch_bounds__(256, 2) void gemm0_quad(
    const float* __restrict__ A0, const float* __restrict__ A1,
    const unsigned short* __restrict__ B0, const unsigned short* __restrict__ B1,
    const unsigned short* __restrict__ B2, const unsigned short* __restrict__ B3,
    const float* b0, const float* b1, const float* b2, const float* b3,
    unsigned short* o0, unsigned short* o1, unsigned short* o2,
    unsigned short* o3, int M0, int M1) {
  __shared__ __attribute__((aligned(16))) unsigned short Xs[64 * 256];
  int a = blockIdx.y;
  const float* A = (a < 2) ? A0 : A1;
  int M = (a < 2) ? M0 : M1;
  int mblk = blockIdx.x * 64;
  if (mblk >= M) return;
  const unsigned short* B = a == 0 ? B0 : a == 1 ? B1 : a == 2 ? B2 : B3;
  const float* bias = a == 0 ? b0 : a == 1 ? b1 : a == 2 ? b2 : b3;
  unsigned short* outb = a == 0 ? o0 : a == 1 ? o1 : a == 2 ? o2 : o3;
  stage_A_f32(Xs, A, M, mblk);
  __syncthreads();
  gemm_compute<0, false>(Xs, B, bias, nullptr, outb, nullptr, M, mblk);
}

// both final GEMMs (out = lrelu(h@Wh^T+bh)+feat) in ONE dispatch.
__global__ __launch_bounds__(256, 2) void gemm1_dual(
    const unsigned short* __restrict__ A0, const unsigned short* __restrict__ A1,
    const unsigned short* __restrict__ Bw, const float* bh,
    const float* __restrict__ r0, const float* __restrict__ r1,
    float* __restrict__ o0, float* __restrict__ o1, int M0, int M1) {
  __shared__ __attribute__((aligned(16))) unsigned short Xs[64 * 256];
  int a = blockIdx.y;
  const unsigned short* A = a ? A1 : A0;
  int M = a ? M1 : M0;
  int mblk = blockIdx.x * 64;
  if (mblk >= M) return;
  stage_A(Xs, A, M, mblk);
  gemm_compute<1, true>(Xs, Bw, bh, a ? r1 : r0, nullptr, a ? o1 : o0, M, mblk);
}

// ---------------- counting-sort CSR build ----------------
// Pass 1: per-block LDS histogram over 512-dst buckets.
__global__ __launch_bounds__(256) void bucketCount_kernel(
    const int* d0, int n0, const int* d1, int n1, const int* d2, int n2,
    const int* d3, int n3, int* __restrict__ bcnt) {
  int a = blockIdx.y;
  const int* dst = a == 0 ? d0 : a == 1 ? d1 : a == 2 ? d2 : d3;
  int n = a == 0 ? n0 : a == 1 ? n1 : a == 2 ? n2 : n3;
  int blk = blockIdx.x;
  if (blk * EPB >= n) return;
  int t = threadIdx.x;
  __shared__ int cnt[NBMAX];
  if (t < NBMAX) cnt[t] = 0;
  __syncthreads();
  int i0 = blk * EPB + t;
#pragma unroll 4
  for (int it = 0; it < EPB / 256; it++) {
    int i = i0 + it * 256;
    if (i < n) atomicAdd(&cnt[dst[i] >> BSH], 1);
  }
  __syncthreads();
  if (t < NBMAX && cnt[t]) atomicAdd(&bcnt[a * NBMAX + t], cnt[t]);
}

// Pass 2: one block scans 4x160 bucket totals -> bbase; writes off[nn]=E.
__global__ __launch_bounds__(256) void bucketScan_kernel(
    const int* __restrict__ bcnt, int* __restrict__ bbase,
    int* o0, int n0, int e0, int* o1, int n1, int e1,
    int* o2, int n2, int e2, int* o3, int n3, int e3) {
  __shared__ int s[256];
  int t = threadIdx.x;
  for (int a = 0; a < 4; a++) {
    int v = (t < NBMAX) ? bcnt[a * NBMAX + t] : 0;
    s[t] = v;
    __syncthreads();
    for (int off = 1; off < 256; off <<= 1) {
      int u = (t >= off) ? s[t - off] : 0;
      __syncthreads();
      s[t] += u;
      __syncthreads();
    }
    if (t < NBMAX)
      bbase[a * (NBMAX + 1) + t] = s[t] - v;
    else if (t == NBMAX)
      bbase[a * (NBMAX + 1) + NBMAX] = s[NBMAX - 1];
    __syncthreads();
  }
  if (t == 0) { o0[n0] = e0; o1[n1] = e1; o2[n2] = e2; o3[n3] = e3; }
}

// Pass 3: scatter edges into bucket-grouped temp (packed src<<9|dstlow).
__global__ __launch_bounds__(256) void bucketA_kernel(
    const int* s0, const int* d0, int n0, unsigned* t0,
    const int* s1, const int* d1, int n1, unsigned* t1,
    const int* s2, const int* d2, int n2, unsigned* t2,
    const int* s3, const int* d3, int n3, unsigned* t3,
    const int* __restrict__ bbase, int* __restrict__ bcur) {
  int a = blockIdx.y;
  const int* src = a == 0 ? s0 : a == 1 ? s1 : a == 2 ? s2 : s3;
  const int* dst = a == 0 ? d0 : a == 1 ? d1 : a == 2 ? d2 : d3;
  int n = a == 0 ? n0 : a == 1 ? n1 : a == 2 ? n2 : n3;
  unsigned* temp = a == 0 ? t0 : a == 1 ? t1 : a == 2 ? t2 : t3;

  int blk = blockIdx.x;
  if (blk * EPB >= n) return;
  int t = threadIdx.x;
  __shared__ int cnt[NBMAX];
  __shared__ int lbase[NBMAX];
  if (t < NBMAX) cnt[t] = 0;
  __syncthreads();

  int i0 = blk * EPB + t;
#pragma unroll 4
  for (int it = 0; it < EPB / 256; it++) {
    int i = i0 + it * 256;
    if (i < n) atomicAdd(&cnt[dst[i] >> BSH], 1);
  }
  __syncthreads();
  if (t < NBMAX) {
    int c = cnt[t];
    int g = c ? atomicAdd(&bcur[a * NBMAX + t], c) : 0;
    lbase[t] = g + bbase[a * (NBMAX + 1) + t];
    cnt[t] = 0;
  }
  __syncthreads();
#pragma unroll 4
  for (int it = 0; it < EPB / 256; it++) {
    int i = i0 + it * 256;
    if (i < n) {
      int d = dst[i];
      int b = d >> BSH;
      int rk = atomicAdd(&cnt[b], 1);
      temp[lbase[b] + rk] = ((unsigned)src[i] << BSH) | (unsigned)(d & (BSZ - 1));
    }
  }
}

// Pass 4: one block per bucket: LDS count+scan of 512 dst slots, write
// off[node] (sequential), scatter src into elist (L2-local window).
__global__ __launch_bounds__(256) void bucketFinal_kernel(
    const unsigned* t0, int* o0, int* e0, int m0,
    const unsigned* t1, int* o1, int* e1, int m1,
    const unsigned* t2, int* o2, int* e2, int m2,
    const unsigned* t3, int* o3, int* e3, int m3,
    const int* __restrict__ bbase) {
  int a = blockIdx.y;
  const unsigned* temp = a == 0 ? t0 : a == 1 ? t1 : a == 2 ? t2 : t3;
  int* offs = a == 0 ? o0 : a == 1 ? o1 : a == 2 ? o2 : o3;
  int* elist = a == 0 ? e0 : a == 1 ? e1 : a == 2 ? e2 : e3;
  int nn = a == 0 ? m0 : a == 1 ? m1 : a == 2 ? m2 : m3;

  int nb = (nn + BSZ - 1) >> BSH;
  int b = blockIdx.x;
  if (b >= nb) return;
  int lo = bbase[a * (NBMAX + 1) + b];
  int hi = bbase[a * (NBMAX + 1) + b + 1];
  int t = threadIdx.x;

  __shared__ int cnt[BSZ];
  __shared__ int psum[BSZ];
  __shared__ int sm[256];
  cnt[t] = 0; cnt[t + 256] = 0;
  __syncthreads();
  for (int i = lo + t; i < hi; i += 256)
    atomicAdd(&cnt[temp[i] & (BSZ - 1)], 1);
  __syncthreads();
  int c0 = cnt[2 * t], c1 = cnt[2 * t + 1];
  int s = c0 + c1;
  sm[t] = s;
  __syncthreads();
  for (int off = 1; off < 256; off <<= 1) {
    int u = (t >= off) ? sm[t - off] : 0;
    __syncthreads();
    sm[t] += u;
    __syncthreads();
  }
  int ex = sm[t] - s;
  psum[2 * t] = ex;
  psum[2 * t + 1] = ex + c0;
  cnt[2 * t] = 0; cnt[2 * t + 1] = 0;   // reuse as cursors
  __syncthreads();

  int node0 = b << BSH;
  if (node0 + 2 * t < nn) offs[node0 + 2 * t] = lo + psum[2 * t];
  if (node0 + 2 * t + 1 < nn) offs[node0 + 2 * t + 1] = lo + psum[2 * t + 1];

  for (int i = lo + t; i < hi; i += 256) {
    unsigned v = temp[i];
    int d = v & (BSZ - 1);
    int rk = atomicAdd(&cnt[d], 1);
    elist[lo + psum[d] + rk] = (int)(v >> BSH);
  }
}

// ---------------- aggregation: one wave per dst node, two etypes fused ------
__device__ __forceinline__ void add8(float* acc, uint4 p) {
  acc[0] += bfbits2f(p.x << 16);
  acc[1] += bfbits2f(p.x & 0xffff0000u);
  acc[2] += bfbits2f(p.y << 16);
  acc[3] += bfbits2f(p.y & 0xffff0000u);
  acc[4] += bfbits2f(p.z << 16);
  acc[5] += bfbits2f(p.z & 0xffff0000u);
  acc[6] += bfbits2f(p.w << 16);
  acc[7] += bfbits2f(p.w & 0xffff0000u);
}

__global__ __launch_bounds__(256) void aggregate_kernel(
    const unsigned short* __restrict__ WhA, const int* __restrict__ offsA,
    const int* __restrict__ elistA, const unsigned short* __restrict__ WhB,
    const int* __restrict__ offsB, const int* __restrict__ elistB,
    unsigned short* __restrict__ hout, int n) {
  int wave = (blockIdx.x * 256 + threadIdx.x) >> 6;
  int lane = threadIdx.x & 63;
  if (wave >= n) return;
  int half = lane >> 5;
  int l32 = lane & 31;
  size_t coff = (size_t)l32 * 8;  // channel offset in shorts

  float accA[8] = {0, 0, 0, 0, 0, 0, 0, 0};
  float accB[8] = {0, 0, 0, 0, 0, 0, 0, 0};
  float scA, scB;

  {
    int e0 = offsA[wave], e1 = offsA[wave + 1];
    scA = 0.5f / fmaxf((float)(e1 - e0), 1.0f);
    int e = e0;
    for (; e + 8 <= e1; e += 8) {
      int s0 = elistA[e + half];
      int s1 = elistA[e + 2 + half];
      int s2 = elistA[e + 4 + half];
      int s3 = elistA[e + 6 + half];
      uint4 p0 = *(const uint4*)(WhA + (size_t)s0 * D + coff);
      uint4 p1 = *(const uint4*)(WhA + (size_t)s1 * D + coff);
      uint4 p2 = *(const uint4*)(WhA + (size_t)s2 * D + coff);
      uint4 p3 = *(const uint4*)(WhA + (size_t)s3 * D + coff);
      add8(accA, p0); add8(accA, p1); add8(accA, p2); add8(accA, p3);
    }
    for (; e + 2 <= e1; e += 2) {
      int s0 = elistA[e + half];
      uint4 p0 = *(const uint4*)(WhA + (size_t)s0 * D + coff);
      add8(accA, p0);
    }
    if (e < e1 && half == 0) {
      int s0 = elistA[e];
      uint4 p0 = *(const uint4*)(WhA + (size_t)s0 * D + coff);
      add8(accA, p0);
    }
  }
  {
    int e0 = offsB[wave], e1 = offsB[wave + 1];
    scB = 0.5f / fmaxf((float)(e1 - e0), 1.0f);
    int e = e0;
    for (; e + 8 <= e1; e += 8) {
      int s0 = elistB[e + half];
      int s1 = elistB[e + 2 + half];
      int s2 = elistB[e + 4 + half];
      int s3 = elistB[e + 6 + half];
      uint4 p0 = *(const uint4*)(WhB + (size_t)s0 * D + coff);
      uint4 p1 = *(const uint4*)(WhB + (size_t)s1 * D + coff);
      uint4 p2 = *(const uint4*)(WhB + (size_t)s2 * D + coff);
      uint4 p3 = *(const uint4*)(WhB + (size_t)s3 * D + coff);
      add8(accB, p0); add8(accB, p1); add8(accB, p2); add8(accB, p3);
    }
    for (; e + 2 <= e1; e += 2) {
      int s0 = elistB[e + half];
      uint4 p0 = *(const uint4*)(WhB + (size_t)s0 * D + coff);
      add8(accB, p0);
    }
    if (e < e1 && half == 0) {
      int s0 = elistB[e];
      uint4 p0 = *(const uint4*)(WhB + (size_t)s0 * D + coff);
      add8(accB, p0);
    }
  }

  float h[8];
#pragma unroll
  for (int j = 0; j < 8; j++) {
    h[j] = accA[j] * scA + accB[j] * scB;
    h[j] += __shfl_down(h[j], 32);
  }
  if (half == 0) {
    uint4 o;
    o.x = (unsigned)f2bf(h[0]) | ((unsigned)f2bf(h[1]) << 16);
    o.y = (unsigned)f2bf(h[2]) | ((unsigned)f2bf(h[3]) << 16);
    o.z = (unsigned)f2bf(h[4]) | ((unsigned)f2bf(h[5]) << 16);
    o.w = (unsigned)f2bf(h[6]) | ((unsigned)f2bf(h[7]) << 16);
    *(uint4*)(hout + (size_t)wave * D + coff) = o;
  }
}

// ---------------- launch ----------------
extern "C" void kernel_launch(void* const* d_in, const int* in_sizes, int n_in,
                              void* d_out, int out_size, void* d_ws,
                              size_t ws_size, hipStream_t stream) {
  const float* feat_table = (const float*)d_in[0];
  const float* feat_column = (const float*)d_in[1];
  const float* Wsrc[5] = {(const float*)d_in[2], (const float*)d_in[4],
                          (const float*)d_in[6], (const float*)d_in[8],
                          (const float*)d_in[10]};
  const float* b_t2c = (const float*)d_in[3];
  const float* b_c2t = (const float*)d_in[5];
  const float* b_c2c = (const float*)d_in[7];
  const float* b_t2t = (const float*)d_in[9];
  const float* b_h = (const float*)d_in[11];
  const int* src_t2c = (const int*)d_in[12];
  const int* dst_t2c = (const int*)d_in[13];
  const int* src_c2t = (const int*)d_in[14];
  const int* dst_c2t = (const int*)d_in[15];
  const int* src_c2c = (const int*)d_in[16];
  const int* dst_c2c = (const int*)d_in[17];
  const int* src_t2t = (const int*)d_in[18];
  const int* dst_t2t = (const int*)d_in[19];

  const int NT = in_sizes[0] / D;
  const int NC = in_sizes[1] / D;
  const int E_t2c = in_sizes[12], E_c2t = in_sizes[14];
  const int E_c2c = in_sizes[16], E_t2t = in_sizes[18];

  char* ws = (char*)d_ws;
  size_t cur = 0;
  auto alloc = [&](size_t bytes) -> void* {
    void* p = ws + cur;
    cur += (bytes + 255) & ~(size_t)255;
    return p;
  };
  unsigned short* Wb[5];
  for (int i = 0; i < 5; i++) Wb[i] = (unsigned short*)alloc((size_t)D * D * 2);
  // scratch region: bucket temp (bucketA->bucketFinal), then h_tab/h_col
  // (aggregate->gemm1). Sized for the larger of the two uses.
  size_t scratchA = sizeof(unsigned) * ((size_t)E_c2t + E_t2t + E_t2c + E_c2c);
  size_t scratchB = (size_t)(NT + NC) * D * 2;
  unsigned short* scr = (unsigned short*)alloc(scratchA > scratchB ? scratchA
                                                                   : scratchB);
  unsigned short* Wh_t2c = (unsigned short*)alloc((size_t)NT * D * 2);
  unsigned short* Wh_c2t = (unsigned short*)alloc((size_t)NC * D * 2);
  unsigned short* Wh_c2c = (unsigned short*)alloc((size_t)NC * D * 2);
  unsigned short* Wh_t2t = (unsigned short*)alloc((size_t)NT * D * 2);
  // bucket counters (zeroed): bcnt[4][160] + bcur[4][160]
  int* bcnt = (int*)alloc(sizeof(int) * 2 * 4 * NBMAX);
  int* bcur = bcnt + 4 * NBMAX;
  int* bbase = (int*)alloc(sizeof(int) * 4 * (NBMAX + 1));
  int* off_c2t = (int*)alloc(sizeof(int) * (NT + 1));
  int* off_t2t = (int*)alloc(sizeof(int) * (NT + 1));
  int* off_t2c = (int*)alloc(sizeof(int) * (NC + 1));
  int* off_c2c = (int*)alloc(sizeof(int) * (NC + 1));
  int* el_c2t = (int*)alloc(sizeof(int) * E_c2t);
  int* el_t2t = (int*)alloc(sizeof(int) * E_t2t);
  int* el_t2c = (int*)alloc(sizeof(int) * E_t2c);
  int* el_c2c = (int*)alloc(sizeof(int) * E_c2c);

  // scratch region aliases (lifetimes disjoint; stream serializes)
  unsigned* tp_c2t = (unsigned*)scr;
  unsigned* tp_t2t = tp_c2t + E_c2t;
  unsigned* tp_t2c = tp_t2t + E_t2t;
  unsigned* tp_c2c = tp_t2c + E_t2c;
  unsigned short* h_tab = scr;
  unsigned short* h_col = scr + (size_t)NT * D;

  hipMemsetAsync(bcnt, 0, sizeof(int) * 2 * 4 * NBMAX, stream);

  // weight casts
  {
    dim3 g((D * D / 4 + 255) / 256, 5);
    cast5_kernel<<<g, 256, 0, stream>>>(Wsrc[0], Wsrc[1], Wsrc[2], Wsrc[3],
                                        Wsrc[4], Wb[0], Wb[1], Wb[2], Wb[3],
                                        Wb[4]);
  }

  // Wh = lrelu(feat @ W^T + b): one etype per block (quad), fused cast.
  {
    dim3 g((max(NT, NC) + 63) / 64, 4);
    gemm0_quad<<<g, 256, 0, stream>>>(
        feat_table, feat_column, Wb[0], Wb[3], Wb[1], Wb[2], b_t2c, b_t2t,
        b_c2t, b_c2c, Wh_t2c, Wh_t2t, Wh_c2t, Wh_c2c, NT, NC);
  }

  // counting-sort CSR build
  int Emax = max(max(E_c2t, E_t2t), max(E_t2c, E_c2c));
  {
    dim3 g((Emax + EPB - 1) / EPB, 4);
    bucketCount_kernel<<<g, 256, 0, stream>>>(dst_c2t, E_c2t, dst_t2t, E_t2t,
                                              dst_t2c, E_t2c, dst_c2c, E_c2c,
                                              bcnt);
  }
  bucketScan_kernel<<<1, 256, 0, stream>>>(
      bcnt, bbase, off_c2t, NT, E_c2t, off_t2t, NT, E_t2t, off_t2c, NC, E_t2c,
      off_c2c, NC, E_c2c);
  {
    dim3 g((Emax + EPB - 1) / EPB, 4);
    bucketA_kernel<<<g, 256, 0, stream>>>(
        src_c2t, dst_c2t, E_c2t, tp_c2t, src_t2t, dst_t2t, E_t2t, tp_t2t,
        src_t2c, dst_t2c, E_t2c, tp_t2c, src_c2c, dst_c2c, E_c2c, tp_c2c,
        bbase, bcur);
  }
  {
    int nbmax = (max(NT, NC) + BSZ - 1) >> BSH;
    dim3 g(nbmax, 4);
    bucketFinal_kernel<<<g, 256, 0, stream>>>(
        tp_c2t, off_c2t, el_c2t, NT, tp_t2t, off_t2t, el_t2t, NT,
        tp_t2c, off_t2c, el_t2c, NC, tp_c2c, off_c2c, el_c2c, NC, bbase);
  }

  // h = 0.5*(meanA + meanB): NC first (big), then NT — separate dispatches
  // keep the gather working set at 51 MB each (merged 102 MB thrashed L2).
  aggregate_kernel<<<(NC + 3) / 4, 256, 0, stream>>>(
      Wh_t2c, off_t2c, el_t2c, Wh_c2c, off_c2c, el_c2c, h_col, NC);
  aggregate_kernel<<<(NT + 3) / 4, 256, 0, stream>>>(
      Wh_c2t, off_c2t, el_c2t, Wh_t2t, off_t2t, el_t2t, h_tab, NT);

  // out = lrelu(h @ W_h^T + b_h) + feat: both ntypes in one dispatch
  float* out_tab = (float*)d_out;
  float* out_col = out_tab + (size_t)NT * D;
  {
    dim3 g((max(NT, NC) + 63) / 64, 2);
    gemm1_dual<<<g, 256, 0, stream>>>(h_tab, h_col, Wb[4], b_h, feat_table,
                                      feat_column, out_tab, out_col, NT, NC);
  }
}